// Round 7
// baseline (216.982 us; speedup 1.0000x reference)
//
#include <hip/hip_runtime.h>

#define D_FEAT 128
#define K_SEG 16
#define EDGE_BLOCKS 2048

typedef float f32x2 __attribute__((ext_vector_type(2)));
typedef float f32x4 __attribute__((ext_vector_type(4)));
typedef __bf16 bf16x8 __attribute__((ext_vector_type(8)));

__device__ __forceinline__ unsigned char fp8_enc(float v) {
    return (unsigned char)(__builtin_amdgcn_cvt_pk_fp8_f32(v, v, 0, false) & 0xff);
}

// ---------------------------------------------------------------------------
// Kernel 1 (node pass, MFMA): one wave computes 16 nodes.
//   logits(16x16) = x_tile(16x128)bf16 @ W(128x16)bf16 via 4 MFMA 16x16x32.
//   Also emits: x fp8 + ||x_q||^2 + S fp8 (edge pass), S fp32 (exact output).
//   Block 0 additionally zeroes the 32-float accumulator + done-counter
//   (replaces the hipMemsetAsync dispatch; edge kernel runs strictly after).
// ---------------------------------------------------------------------------
__global__ void node_pass_kernel(const float* __restrict__ x,
                                 const float* __restrict__ W,   // (D,K) row-major
                                 const float* __restrict__ b,
                                 float* __restrict__ S_out,
                                 unsigned char* __restrict__ xq,
                                 unsigned char* __restrict__ Sq,
                                 float* __restrict__ nq,
                                 float* __restrict__ acc_glob,  // 32 f + counter
                                 int N)
{
    if (blockIdx.x == 0 && threadIdx.x < 33) {
        if (threadIdx.x < 32) acc_glob[threadIdx.x] = 0.f;
        else ((unsigned*)acc_glob)[32] = 0u;   // completion counter
    }

    const int lane = threadIdx.x & 63;
    const int m = lane & 15;      // row within tile (A) / col (B,C)
    const int q = lane >> 4;      // quad

    // W fragments (once, kept in VGPRs): wf[kb][j] = W[32kb+8q+j][m]
    bf16x8 wf[4];
    #pragma unroll
    for (int kb = 0; kb < 4; kb++)
        #pragma unroll
        for (int j = 0; j < 8; j++)
            wf[kb][j] = (__bf16)W[(32 * kb + 8 * q + j) * K_SEG + m];
    const float bc = b[m];

    const int tile = blockIdx.x * (blockDim.x >> 6) + (threadIdx.x >> 6);
    const int ntiles = (N + 15) >> 4;
    if (tile >= ntiles) return;

    const int row = tile * 16 + m;                 // node this lane loads
    const int rowc = row < N ? row : N - 1;
    const float* xr = x + (size_t)rowc * D_FEAT;

    f32x4 acc = {0.f, 0.f, 0.f, 0.f};
    float nrm = 0.f;
    #pragma unroll
    for (int kb = 0; kb < 4; kb++) {
        const int f0 = 32 * kb + 8 * q;
        float4 v0 = *(const float4*)(xr + f0);
        float4 v1 = *(const float4*)(xr + f0 + 4);

        bf16x8 af;
        af[0] = (__bf16)v0.x; af[1] = (__bf16)v0.y;
        af[2] = (__bf16)v0.z; af[3] = (__bf16)v0.w;
        af[4] = (__bf16)v1.x; af[5] = (__bf16)v1.y;
        af[6] = (__bf16)v1.z; af[7] = (__bf16)v1.w;

        acc = __builtin_amdgcn_mfma_f32_16x16x32_bf16(af, wf[kb], acc, 0, 0, 0);

        unsigned lo = __builtin_amdgcn_cvt_pk_fp8_f32(v0.x, v0.y, 0, false);
        lo = __builtin_amdgcn_cvt_pk_fp8_f32(v0.z, v0.w, lo, true);
        unsigned hi = __builtin_amdgcn_cvt_pk_fp8_f32(v1.x, v1.y, 0, false);
        hi = __builtin_amdgcn_cvt_pk_fp8_f32(v1.z, v1.w, hi, true);
        f32x2 d0 = __builtin_amdgcn_cvt_pk_f32_fp8((int)lo, false);
        f32x2 d1 = __builtin_amdgcn_cvt_pk_f32_fp8((int)lo, true);
        f32x2 d2 = __builtin_amdgcn_cvt_pk_f32_fp8((int)hi, false);
        f32x2 d3 = __builtin_amdgcn_cvt_pk_f32_fp8((int)hi, true);
        nrm = fmaf(d0.x, d0.x, nrm); nrm = fmaf(d0.y, d0.y, nrm);
        nrm = fmaf(d1.x, d1.x, nrm); nrm = fmaf(d1.y, d1.y, nrm);
        nrm = fmaf(d2.x, d2.x, nrm); nrm = fmaf(d2.y, d2.y, nrm);
        nrm = fmaf(d3.x, d3.x, nrm); nrm = fmaf(d3.y, d3.y, nrm);

        if (row < N) {
            uint2 pk; pk.x = lo; pk.y = hi;
            *(uint2*)(xq + (size_t)row * D_FEAT + f0) = pk;
        }
    }

    nrm += __shfl_xor(nrm, 16, 64);
    nrm += __shfl_xor(nrm, 32, 64);
    if (q == 0 && row < N) nq[row] = nrm;

    // softmax per C row (over the 16 lanes of each quad)
    #pragma unroll
    for (int r = 0; r < 4; r++) {
        float l = acc[r] + bc;
        float mx = l;
        mx = fmaxf(mx, __shfl_xor(mx, 1, 64));
        mx = fmaxf(mx, __shfl_xor(mx, 2, 64));
        mx = fmaxf(mx, __shfl_xor(mx, 4, 64));
        mx = fmaxf(mx, __shfl_xor(mx, 8, 64));
        float e = __expf(l - mx);
        float sm = e;
        sm += __shfl_xor(sm, 1, 64);
        sm += __shfl_xor(sm, 2, 64);
        sm += __shfl_xor(sm, 4, 64);
        sm += __shfl_xor(sm, 8, 64);
        float p = e / sm;
        int node = tile * 16 + 4 * q + r;
        if (node < N) {
            S_out[(size_t)node * K_SEG + m] = p;        // exact fp32 output
            Sq[(size_t)node * K_SEG + m] = fp8_enc(p);  // fp8 edge copy
        }
    }
}

// ---------------------------------------------------------------------------
// Kernel 2: edge pass, fp8 x + fp8 S, norm-trick, 4x unrolled.
// 8 lanes per edge; lane j: chunk [16j,16j+16), segments {2j,2j+1}.
//   dsq = ||s||^2 + ||t||^2 - 2 s.t   (all over quantized values)
//   a[k] += w*S[s,k];  c[k] += w*S[s,k]*S[t,k];  cut = a - c
// Block reduce -> 32 atomicAdds into acc_glob; LAST block (completion
// counter) computes the loss inline via atomic reads (L2-coherent) and
// writes out[0] — replaces the finalize dispatch.
// ---------------------------------------------------------------------------
__global__ void edge_kernel(const uint4* __restrict__ xq,          // 8 uint4/node
                            const int* __restrict__ ei,
                            const unsigned short* __restrict__ Sq, // 8 ushort/node
                            const float* __restrict__ nq,
                            float* __restrict__ acc_glob,          // 32 f + counter
                            float* __restrict__ out,
                            int E)
{
    const int lane = threadIdx.x & 63;
    const int sub  = lane >> 3;   // edge within oct (0..7)
    const int j    = lane & 7;    // chunk / segment-pair id
    const int wave_in_block = threadIdx.x >> 6;
    const int gwave  = blockIdx.x * (blockDim.x >> 6) + wave_in_block;
    const int nwaves = gridDim.x * (blockDim.x >> 6);
    const int* __restrict__ src_p = ei;
    const int* __restrict__ tgt_p = ei + E;

    float a0 = 0.f, a1 = 0.f, c0 = 0.f, c1 = 0.f;

    for (int base = gwave * 32; base < E; base += nwaves * 32) {
        bool valid[4];
        uint4 xs[4], xt[4];
        unsigned ss[4], st[4];
        float nn[4];
        #pragma unroll
        for (int u = 0; u < 4; u++) {
            int e = base + 8 * u + sub;
            valid[u] = (e < E);
            int ec = valid[u] ? e : 0;
            int s = src_p[ec], t = tgt_p[ec];
            xs[u] = xq[(size_t)s * 8 + j];
            xt[u] = xq[(size_t)t * 8 + j];
            ss[u] = Sq[(size_t)s * 8 + j];
            st[u] = Sq[(size_t)t * 8 + j];
            nn[u] = nq[s] + nq[t];
        }

        float dot[4];
        #pragma unroll
        for (int u = 0; u < 4; u++) {
            const unsigned* ua = (const unsigned*)&xs[u];
            const unsigned* ub = (const unsigned*)&xt[u];
            float d = 0.f;
            #pragma unroll
            for (int qq = 0; qq < 4; qq++) {
                f32x2 alo = __builtin_amdgcn_cvt_pk_f32_fp8((int)ua[qq], false);
                f32x2 ahi = __builtin_amdgcn_cvt_pk_f32_fp8((int)ua[qq], true);
                f32x2 blo = __builtin_amdgcn_cvt_pk_f32_fp8((int)ub[qq], false);
                f32x2 bhi = __builtin_amdgcn_cvt_pk_f32_fp8((int)ub[qq], true);
                d = fmaf(alo.x, blo.x, d);
                d = fmaf(alo.y, blo.y, d);
                d = fmaf(ahi.x, bhi.x, d);
                d = fmaf(ahi.y, bhi.y, d);
            }
            dot[u] = d;
        }
        #pragma unroll
        for (int dd = 1; dd < 8; dd <<= 1)
            #pragma unroll
            for (int u = 0; u < 4; u++)
                dot[u] += __shfl_xor(dot[u], dd, 64);

        #pragma unroll
        for (int u = 0; u < 4; u++) {
            float dsq = nn[u] - 2.f * dot[u];
            float w = valid[u] ? __expf(-0.5f * dsq) : 0.f;
            f32x2 ps = __builtin_amdgcn_cvt_pk_f32_fp8((int)ss[u], false);
            f32x2 pt = __builtin_amdgcn_cvt_pk_f32_fp8((int)st[u], false);
            float t0 = w * ps.x; a0 += t0; c0 = fmaf(t0, pt.x, c0);
            float t1 = w * ps.y; a1 += t1; c1 = fmaf(t1, pt.y, c1);
        }
    }

    // fold the 8 sub-groups (same j, different edges)
    #pragma unroll
    for (int d = 8; d < 64; d <<= 1) {
        a0 += __shfl_xor(a0, d, 64);
        a1 += __shfl_xor(a1, d, 64);
        c0 += __shfl_xor(c0, d, 64);
        c1 += __shfl_xor(c1, d, 64);
    }

    __shared__ float red[4][32];
    if (lane < 8) {
        red[wave_in_block][2 * j]          = a0;
        red[wave_in_block][2 * j + 1]      = a1;
        red[wave_in_block][16 + 2 * j]     = c0;
        red[wave_in_block][16 + 2 * j + 1] = c1;
    }
    __syncthreads();
    if (threadIdx.x < 32) {
        float v = red[0][threadIdx.x] + red[1][threadIdx.x]
                + red[2][threadIdx.x] + red[3][threadIdx.x];
        atomicAdd(&acc_glob[threadIdx.x], v);
    }
    __syncthreads();              // all 32 atomics of this block issued

    // last-block-done finalize (device-scope counter; m20: atomics are
    // device-scope by default, safe cross-XCD)
    if (threadIdx.x == 0) {
        __threadfence();
        unsigned done = atomicAdd((unsigned*)(acc_glob + 32), 1u);
        if (done == gridDim.x - 1) {
            float loss = 0.f;
            for (int kk = 0; kk < K_SEG; kk++) {
                float a = atomicAdd(&acc_glob[kk], 0.f);        // coherent read
                float c = atomicAdd(&acc_glob[kk + K_SEG], 0.f);
                if (a > 1e-8f) loss += (a - c) / a;
            }
            out[0] = loss;
        }
    }
}

extern "C" void kernel_launch(void* const* d_in, const int* in_sizes, int n_in,
                              void* d_out, int out_size, void* d_ws, size_t ws_size,
                              hipStream_t stream) {
    const float* x  = (const float*)d_in[0];
    const int*   ei = (const int*)d_in[1];
    // d_in[2] = num_expected_segments (scalar, ==16, hardcoded)
    const float* W  = (const float*)d_in[3];
    const float* b  = (const float*)d_in[4];
    float* out = (float*)d_out;

    int N = in_sizes[0] / D_FEAT;
    int E = in_sizes[1] / 2;

    float* S = out + 1;   // S output doubles as the fp32 S buffer

    // workspace layout (all 16B-aligned)
    float* acc = (float*)d_ws;                                   // 32 f + counter
    unsigned char* xq = (unsigned char*)d_ws + 256;              // N*128 B fp8 x
    unsigned char* Sq = xq + (size_t)N * D_FEAT;                 // N*16  B fp8 S
    float* nq = (float*)(Sq + (size_t)N * K_SEG);                // N*4   B norms

    int ntiles = (N + 15) / 16;              // one wave per 16-node tile
    int nblocks = (ntiles + 3) / 4;          // 4 waves per block
    node_pass_kernel<<<nblocks, 256, 0, stream>>>(x, W, b, S, xq, Sq, nq, acc, N);

    edge_kernel<<<EDGE_BLOCKS, 256, 0, stream>>>((const uint4*)xq, ei,
                                                 (const unsigned short*)Sq,
                                                 nq, acc, out, E);
}

// Round 8
// 161.215 us; speedup vs baseline: 1.3459x; 1.3459x over previous
//
#include <hip/hip_runtime.h>

#define D_FEAT 128
#define K_SEG 16
#define EDGE_BLOCKS 2048

typedef float f32x2 __attribute__((ext_vector_type(2)));
typedef float f32x4 __attribute__((ext_vector_type(4)));
typedef __bf16 bf16x8 __attribute__((ext_vector_type(8)));

__device__ __forceinline__ unsigned char fp8_enc(float v) {
    return (unsigned char)(__builtin_amdgcn_cvt_pk_fp8_f32(v, v, 0, false) & 0xff);
}

// ---------------------------------------------------------------------------
// Kernel 1 (node pass, MFMA): one wave computes 16 nodes.
//   logits(16x16) = x_tile(16x128)bf16 @ W(128x16)bf16 via 4 MFMA 16x16x32.
//   Also emits: x fp8 + ||x_q||^2 + S fp8 (edge pass), S fp32 (exact output).
//   Block 0 additionally zeroes the 32-float accumulator + done-counter.
// ---------------------------------------------------------------------------
__global__ void node_pass_kernel(const float* __restrict__ x,
                                 const float* __restrict__ W,   // (D,K) row-major
                                 const float* __restrict__ b,
                                 float* __restrict__ S_out,
                                 unsigned char* __restrict__ xq,
                                 unsigned char* __restrict__ Sq,
                                 float* __restrict__ nq,
                                 float* __restrict__ acc_glob,  // 32 f + counter
                                 int N)
{
    if (blockIdx.x == 0 && threadIdx.x < 33) {
        if (threadIdx.x < 32) acc_glob[threadIdx.x] = 0.f;
        else ((unsigned*)acc_glob)[32] = 0u;   // completion counter
    }

    const int lane = threadIdx.x & 63;
    const int m = lane & 15;      // row within tile (A) / col (B,C)
    const int q = lane >> 4;      // quad

    // W fragments (once, kept in VGPRs): wf[kb][j] = W[32kb+8q+j][m]
    bf16x8 wf[4];
    #pragma unroll
    for (int kb = 0; kb < 4; kb++)
        #pragma unroll
        for (int j = 0; j < 8; j++)
            wf[kb][j] = (__bf16)W[(32 * kb + 8 * q + j) * K_SEG + m];
    const float bc = b[m];

    const int tile = blockIdx.x * (blockDim.x >> 6) + (threadIdx.x >> 6);
    const int ntiles = (N + 15) >> 4;
    if (tile >= ntiles) return;

    const int row = tile * 16 + m;                 // node this lane loads
    const int rowc = row < N ? row : N - 1;
    const float* xr = x + (size_t)rowc * D_FEAT;

    f32x4 acc = {0.f, 0.f, 0.f, 0.f};
    float nrm = 0.f;
    #pragma unroll
    for (int kb = 0; kb < 4; kb++) {
        const int f0 = 32 * kb + 8 * q;
        float4 v0 = *(const float4*)(xr + f0);
        float4 v1 = *(const float4*)(xr + f0 + 4);

        bf16x8 af;
        af[0] = (__bf16)v0.x; af[1] = (__bf16)v0.y;
        af[2] = (__bf16)v0.z; af[3] = (__bf16)v0.w;
        af[4] = (__bf16)v1.x; af[5] = (__bf16)v1.y;
        af[6] = (__bf16)v1.z; af[7] = (__bf16)v1.w;

        acc = __builtin_amdgcn_mfma_f32_16x16x32_bf16(af, wf[kb], acc, 0, 0, 0);

        unsigned lo = __builtin_amdgcn_cvt_pk_fp8_f32(v0.x, v0.y, 0, false);
        lo = __builtin_amdgcn_cvt_pk_fp8_f32(v0.z, v0.w, lo, true);
        unsigned hi = __builtin_amdgcn_cvt_pk_fp8_f32(v1.x, v1.y, 0, false);
        hi = __builtin_amdgcn_cvt_pk_fp8_f32(v1.z, v1.w, hi, true);
        f32x2 d0 = __builtin_amdgcn_cvt_pk_f32_fp8((int)lo, false);
        f32x2 d1 = __builtin_amdgcn_cvt_pk_f32_fp8((int)lo, true);
        f32x2 d2 = __builtin_amdgcn_cvt_pk_f32_fp8((int)hi, false);
        f32x2 d3 = __builtin_amdgcn_cvt_pk_f32_fp8((int)hi, true);
        nrm = fmaf(d0.x, d0.x, nrm); nrm = fmaf(d0.y, d0.y, nrm);
        nrm = fmaf(d1.x, d1.x, nrm); nrm = fmaf(d1.y, d1.y, nrm);
        nrm = fmaf(d2.x, d2.x, nrm); nrm = fmaf(d2.y, d2.y, nrm);
        nrm = fmaf(d3.x, d3.x, nrm); nrm = fmaf(d3.y, d3.y, nrm);

        if (row < N) {
            uint2 pk; pk.x = lo; pk.y = hi;
            *(uint2*)(xq + (size_t)row * D_FEAT + f0) = pk;
        }
    }

    nrm += __shfl_xor(nrm, 16, 64);
    nrm += __shfl_xor(nrm, 32, 64);
    if (q == 0 && row < N) nq[row] = nrm;

    // softmax per C row (over the 16 lanes of each quad)
    #pragma unroll
    for (int r = 0; r < 4; r++) {
        float l = acc[r] + bc;
        float mx = l;
        mx = fmaxf(mx, __shfl_xor(mx, 1, 64));
        mx = fmaxf(mx, __shfl_xor(mx, 2, 64));
        mx = fmaxf(mx, __shfl_xor(mx, 4, 64));
        mx = fmaxf(mx, __shfl_xor(mx, 8, 64));
        float e = __expf(l - mx);
        float sm = e;
        sm += __shfl_xor(sm, 1, 64);
        sm += __shfl_xor(sm, 2, 64);
        sm += __shfl_xor(sm, 4, 64);
        sm += __shfl_xor(sm, 8, 64);
        float p = e / sm;
        int node = tile * 16 + 4 * q + r;
        if (node < N) {
            S_out[(size_t)node * K_SEG + m] = p;        // exact fp32 output
            Sq[(size_t)node * K_SEG + m] = fp8_enc(p);  // fp8 edge copy
        }
    }
}

// ---------------------------------------------------------------------------
// Kernel 2: edge pass, fp8 x + fp8 S, norm-trick, 4x unrolled.
// 8 lanes per edge; lane j: chunk [16j,16j+16), segments {2j,2j+1}.
//   dsq = ||s||^2 + ||t||^2 - 2 s.t   (all over quantized values)
//   a[k] += w*S[s,k];  c[k] += w*S[s,k]*S[t,k];  cut = a - c
// Block reduce -> 32 atomicAdds; last block finalizes via coherent atomic
// reads. NO __threadfence(): R7 showed it costs 2.2x (per-block L2 flush,
// gather hit-rate destroyed). Ordering is already guaranteed: compiler emits
// s_waitcnt vmcnt(0) before s_barrier, so the 32 data atomics have COMPLETED
// at the coherence point before the post-barrier counter atomic issues.
// ---------------------------------------------------------------------------
__global__ void edge_kernel(const uint4* __restrict__ xq,          // 8 uint4/node
                            const int* __restrict__ ei,
                            const unsigned short* __restrict__ Sq, // 8 ushort/node
                            const float* __restrict__ nq,
                            float* __restrict__ acc_glob,          // 32 f + counter
                            float* __restrict__ out,
                            int E)
{
    const int lane = threadIdx.x & 63;
    const int sub  = lane >> 3;   // edge within oct (0..7)
    const int j    = lane & 7;    // chunk / segment-pair id
    const int wave_in_block = threadIdx.x >> 6;
    const int gwave  = blockIdx.x * (blockDim.x >> 6) + wave_in_block;
    const int nwaves = gridDim.x * (blockDim.x >> 6);
    const int* __restrict__ src_p = ei;
    const int* __restrict__ tgt_p = ei + E;

    float a0 = 0.f, a1 = 0.f, c0 = 0.f, c1 = 0.f;

    for (int base = gwave * 32; base < E; base += nwaves * 32) {
        bool valid[4];
        uint4 xs[4], xt[4];
        unsigned ss[4], st[4];
        float nn[4];
        #pragma unroll
        for (int u = 0; u < 4; u++) {
            int e = base + 8 * u + sub;
            valid[u] = (e < E);
            int ec = valid[u] ? e : 0;
            int s = src_p[ec], t = tgt_p[ec];
            xs[u] = xq[(size_t)s * 8 + j];
            xt[u] = xq[(size_t)t * 8 + j];
            ss[u] = Sq[(size_t)s * 8 + j];
            st[u] = Sq[(size_t)t * 8 + j];
            nn[u] = nq[s] + nq[t];
        }

        float dot[4];
        #pragma unroll
        for (int u = 0; u < 4; u++) {
            const unsigned* ua = (const unsigned*)&xs[u];
            const unsigned* ub = (const unsigned*)&xt[u];
            float d = 0.f;
            #pragma unroll
            for (int qq = 0; qq < 4; qq++) {
                f32x2 alo = __builtin_amdgcn_cvt_pk_f32_fp8((int)ua[qq], false);
                f32x2 ahi = __builtin_amdgcn_cvt_pk_f32_fp8((int)ua[qq], true);
                f32x2 blo = __builtin_amdgcn_cvt_pk_f32_fp8((int)ub[qq], false);
                f32x2 bhi = __builtin_amdgcn_cvt_pk_f32_fp8((int)ub[qq], true);
                d = fmaf(alo.x, blo.x, d);
                d = fmaf(alo.y, blo.y, d);
                d = fmaf(ahi.x, bhi.x, d);
                d = fmaf(ahi.y, bhi.y, d);
            }
            dot[u] = d;
        }
        #pragma unroll
        for (int dd = 1; dd < 8; dd <<= 1)
            #pragma unroll
            for (int u = 0; u < 4; u++)
                dot[u] += __shfl_xor(dot[u], dd, 64);

        #pragma unroll
        for (int u = 0; u < 4; u++) {
            float dsq = nn[u] - 2.f * dot[u];
            float w = valid[u] ? __expf(-0.5f * dsq) : 0.f;
            f32x2 ps = __builtin_amdgcn_cvt_pk_f32_fp8((int)ss[u], false);
            f32x2 pt = __builtin_amdgcn_cvt_pk_f32_fp8((int)st[u], false);
            float t0 = w * ps.x; a0 += t0; c0 = fmaf(t0, pt.x, c0);
            float t1 = w * ps.y; a1 += t1; c1 = fmaf(t1, pt.y, c1);
        }
    }

    // fold the 8 sub-groups (same j, different edges)
    #pragma unroll
    for (int d = 8; d < 64; d <<= 1) {
        a0 += __shfl_xor(a0, d, 64);
        a1 += __shfl_xor(a1, d, 64);
        c0 += __shfl_xor(c0, d, 64);
        c1 += __shfl_xor(c1, d, 64);
    }

    __shared__ float red[4][32];
    if (lane < 8) {
        red[wave_in_block][2 * j]          = a0;
        red[wave_in_block][2 * j + 1]      = a1;
        red[wave_in_block][16 + 2 * j]     = c0;
        red[wave_in_block][16 + 2 * j + 1] = c1;
    }
    __syncthreads();
    if (threadIdx.x < 32) {
        float v = red[0][threadIdx.x] + red[1][threadIdx.x]
                + red[2][threadIdx.x] + red[3][threadIdx.x];
        atomicAdd(&acc_glob[threadIdx.x], v);
    }
    __syncthreads();   // barrier drains vmcnt -> data atomics complete

    if (threadIdx.x == 0) {
        unsigned done = atomicAdd((unsigned*)(acc_glob + 32), 1u);
        if (done == gridDim.x - 1) {
            float loss = 0.f;
            for (int kk = 0; kk < K_SEG; kk++) {
                float a = atomicAdd(&acc_glob[kk], 0.f);        // coherent read
                float c = atomicAdd(&acc_glob[kk + K_SEG], 0.f);
                if (a > 1e-8f) loss += (a - c) / a;
            }
            out[0] = loss;
        }
    }
}

extern "C" void kernel_launch(void* const* d_in, const int* in_sizes, int n_in,
                              void* d_out, int out_size, void* d_ws, size_t ws_size,
                              hipStream_t stream) {
    const float* x  = (const float*)d_in[0];
    const int*   ei = (const int*)d_in[1];
    // d_in[2] = num_expected_segments (scalar, ==16, hardcoded)
    const float* W  = (const float*)d_in[3];
    const float* b  = (const float*)d_in[4];
    float* out = (float*)d_out;

    int N = in_sizes[0] / D_FEAT;
    int E = in_sizes[1] / 2;

    float* S = out + 1;   // S output doubles as the fp32 S buffer

    // workspace layout (all 16B-aligned)
    float* acc = (float*)d_ws;                                   // 32 f + counter
    unsigned char* xq = (unsigned char*)d_ws + 256;              // N*128 B fp8 x
    unsigned char* Sq = xq + (size_t)N * D_FEAT;                 // N*16  B fp8 S
    float* nq = (float*)(Sq + (size_t)N * K_SEG);                // N*4   B norms

    int ntiles = (N + 15) / 16;              // one wave per 16-node tile
    int nblocks = (ntiles + 3) / 4;          // 4 waves per block
    node_pass_kernel<<<nblocks, 256, 0, stream>>>(x, W, b, S, xq, Sq, nq, acc, N);

    edge_kernel<<<EDGE_BLOCKS, 256, 0, stream>>>((const uint4*)xq, ei,
                                                 (const unsigned short*)Sq,
                                                 nq, acc, out, E);
}